// Round 21
// baseline (117.777 us; speedup 1.0000x reference)
//
#include <hip/hip_runtime.h>
#include <hip/hip_bf16.h>

// WindowAttention3D: B=64 windows, N=512 tokens, H=6 heads, D=32, C=192.
// 3 launches (R20 baseline; mid qkv K-loops MERGED for 3x per-wave ILP):
//   k1 prep_kernel: maskbits || wconv || cpb MLP (tab6, padded 8/row)
//   k2 mid_kernel:  qkv bf16-MFMA GEMM (1024 blocks x 3 waves, wave=region;
//                   all 3 nc-chunks accumulate in ONE merged K-loop with
//                   acc[3][2][4] -> 72 independent w-loads / 24 MFMA streams
//                   visible to the scheduler; epilogues deferred) ||
//                   bias_expand (x4 gather)
//   k3 attn_kernel: 4 waves x 64 q-rows, 8 kb-iters, no LDS; ones-MFMA
//                   row-sum, bit-mask sign-extract+AND, setprio, swapped
//                   QK^T, PERMUTED f16x8 bias, permlane P relayout.

typedef __bf16 bf16x8 __attribute__((ext_vector_type(8)));
typedef __bf16 bf16x4v __attribute__((ext_vector_type(4)));
typedef float  f32x4  __attribute__((ext_vector_type(4)));
typedef _Float16 f16x4 __attribute__((ext_vector_type(4)));
typedef _Float16 f16x8 __attribute__((ext_vector_type(8)));
typedef unsigned uint2v __attribute__((ext_vector_type(2)));
typedef int int4v __attribute__((ext_vector_type(4)));
typedef unsigned long long u64;

#define LOG2E 1.4426950408889634f

__device__ __forceinline__ bf16x8 cvt2_bf16x8(f32x4 a, f32x4 b) {
  bf16x8 r;
  r[0] = (__bf16)a[0]; r[1] = (__bf16)a[1]; r[2] = (__bf16)a[2]; r[3] = (__bf16)a[3];
  r[4] = (__bf16)b[0]; r[5] = (__bf16)b[1]; r[6] = (__bf16)b[2]; r[7] = (__bf16)b[3];
  return r;
}

__device__ __forceinline__ unsigned pack2bf(float a, float b) {
  unsigned short ua = __builtin_bit_cast(unsigned short, (__bf16)a);
  unsigned short ub = __builtin_bit_cast(unsigned short, (__bf16)b);
  return (unsigned)ua | ((unsigned)ub << 16);
}

__device__ __forceinline__ bf16x8 frag_from_words(unsigned w0, unsigned w1,
                                                  unsigned w2, unsigned w3) {
  union { unsigned u[4]; bf16x8 v; } f;
  f.u[0] = w0; f.u[1] = w1; f.u[2] = w2; f.u[3] = w3;
  return f.v;
}

// ---------------- k1: prep (maskbits || wconv || cpb) -----------------------
#define PREP_MB    2048
#define PREP_WCONV 108
#define PREP_CPB   3375
#define PREP_GRID  (PREP_MB + PREP_WCONV + PREP_CPB)   // 5531

__global__ __launch_bounds__(256) void prep_kernel(
    const float* __restrict__ w, __bf16* __restrict__ wbf,
    const float* __restrict__ table, const float* __restrict__ w1,
    const float* __restrict__ b1, const float* __restrict__ w2,
    float* __restrict__ tab6,          // (3375,8) padded rows
    const float* __restrict__ m, u64* __restrict__ bits)
{
  __shared__ float red[4][6];
  int blk = blockIdx.x;
  if (blk < PREP_MB) {
    // maskbits: 8 consecutive elems/thread -> byte; 8 lanes -> one u64 word.
    int li8 = threadIdx.x & 7;
    for (size_t t = (size_t)blk * 256 + threadIdx.x;
         t < 2097152ull; t += (size_t)PREP_MB * 256) {
      const float* mp = m + t * 8;
      f32x4 v0 = *(const f32x4*)mp;
      f32x4 v1 = *(const f32x4*)(mp + 4);
      unsigned byte =
          (v0[0] == 0.f ? 1u : 0u)  | (v0[1] == 0.f ? 2u : 0u) |
          (v0[2] == 0.f ? 4u : 0u)  | (v0[3] == 0.f ? 8u : 0u) |
          (v1[0] == 0.f ? 16u : 0u) | (v1[1] == 0.f ? 32u : 0u) |
          (v1[2] == 0.f ? 64u : 0u) | (v1[3] == 0.f ? 128u : 0u);
      u64 part = (u64)byte << (8 * li8);
      part |= __shfl_xor(part, 1);
      part |= __shfl_xor(part, 2);
      part |= __shfl_xor(part, 4);
      if (li8 == 0) {
        int w_ = (int)(t >> 3);          // word index
        int b = w_ >> 12, i = (w_ >> 3) & 511, jw = w_ & 7;
        bits[(((size_t)b * 8 + jw) << 9) + i] = part;
      }
    }
  } else if (blk < PREP_MB + PREP_WCONV) {
    int t = (blk - PREP_MB) * 256 + threadIdx.x;
    f32x4 v = *(const f32x4*)(w + (size_t)t * 4);
    bf16x4v o;
    o[0] = (__bf16)v[0]; o[1] = (__bf16)v[1]; o[2] = (__bf16)v[2]; o[3] = (__bf16)v[3];
    *(bf16x4v*)(wbf + (size_t)t * 4) = o;
  } else {
    int p = blk - PREP_MB - PREP_WCONV;
    float c0 = table[p * 3 + 0], c1 = table[p * 3 + 1], c2 = table[p * 3 + 2];
    float acc[6] = {0.f, 0.f, 0.f, 0.f, 0.f, 0.f};
#pragma unroll
    for (int jj = 0; jj < 2; ++jj) {
      int j = threadIdx.x + jj * 256;
      float hv = w1[j * 3 + 0] * c0 + w1[j * 3 + 1] * c1 + w1[j * 3 + 2] * c2 + b1[j];
      hv = fmaxf(hv, 0.0f);
#pragma unroll
      for (int t = 0; t < 6; ++t) acc[t] += w2[t * 512 + j] * hv;
    }
#pragma unroll
    for (int t = 0; t < 6; ++t) {
      acc[t] += __shfl_xor(acc[t], 1);
      acc[t] += __shfl_xor(acc[t], 2);
      acc[t] += __shfl_xor(acc[t], 4);
      acc[t] += __shfl_xor(acc[t], 8);
      acc[t] += __shfl_xor(acc[t], 16);
      acc[t] += __shfl_xor(acc[t], 32);
    }
    int wave = threadIdx.x >> 6;
    if ((threadIdx.x & 63) == 0)
#pragma unroll
      for (int t = 0; t < 6; ++t) red[wave][t] = acc[t];
    __syncthreads();
    if (threadIdx.x < 6) {
      int t = threadIdx.x;
      float s = red[0][t] + red[1][t] + red[2][t] + red[3][t];
      float sig = 16.0f / (1.0f + expf(-s));
      tab6[p * 8 + t] = sig * LOG2E;    // pre-scale by log2e; row pitch 8
    }
  }
}

// ---------------- k2: mid (qkv merged K-loop || bias_expand) ----------------
#define MID_QKV  1024
#define MID_BIAS 342
#define MID_GRID (MID_QKV + MID_BIAS)   // 1366

__global__ __launch_bounds__(192) void mid_kernel(
    const float* __restrict__ x,       // (32768,192) fp32
    const __bf16* __restrict__ wbf,    // (576,192) bf16
    const float* __restrict__ qb,      // (192)
    const float* __restrict__ vb,      // (192)
    __bf16* __restrict__ Qo,           // (64*6,512,32)
    __bf16* __restrict__ Ko,           // (64*6,512,32)
    __bf16* __restrict__ Vt,           // (64*6,32,512)
    const int* __restrict__ relidx,    // (512,512)
    const float* __restrict__ tab6,    // (3375,8) padded
    _Float16* __restrict__ biasH)      // (6,512,512) fp16, PERMUTED, *LOG2E
{
  __shared__ __bf16 tile[2][32][72];   // per-wave private transpose staging
  if (blockIdx.x >= MID_QKV) {
    // ---- bias_expand x4: 4 consecutive output p (same i) per thread.
    // p = jblk*64 + g*16 + kf*4 + t  <-  j = jblk*64 + kf*16 + g*4 + t
    for (int q4 = (blockIdx.x - MID_QKV) * 192 + threadIdx.x; q4 < 65536;
         q4 += MID_BIAS * 192) {
      int ij = q4 * 4;
      int i = ij >> 9, p = ij & 511;
      int jblk = p >> 6, g = (p >> 4) & 3, kf = (p >> 2) & 3;
      int j = (jblk << 6) + kf * 16 + g * 4;
      int4v idx4 = *(const int4v*)(relidx + (i << 9) + j);
      float val[6][4];
#pragma unroll
      for (int u = 0; u < 4; ++u) {
        f32x4 lo = *(const f32x4*)(tab6 + (size_t)idx4[u] * 8);
        f32x4 hi = *(const f32x4*)(tab6 + (size_t)idx4[u] * 8 + 4);
        val[0][u] = lo[0]; val[1][u] = lo[1]; val[2][u] = lo[2];
        val[3][u] = lo[3]; val[4][u] = hi[0]; val[5][u] = hi[1];
      }
#pragma unroll
      for (int t6 = 0; t6 < 6; ++t6) {
        f16x4 o = {(_Float16)val[t6][0], (_Float16)val[t6][1],
                   (_Float16)val[t6][2], (_Float16)val[t6][3]};
        *(f16x4*)(biasH + (size_t)t6 * 262144 + ij) = o;
      }
    }
    return;
  }
  // ---- qkv: merged K-loop over all 3 nc-chunks (3x per-wave ILP).
  const float CQ = 0.17677669529663687f * LOG2E;  // 1/sqrt(32) * log2e
  int lane = threadIdx.x & 63, wave = threadIdx.x >> 6;
  int g = lane >> 4, li = lane & 15;
  int rowbase = blockIdx.x * 32;
  int b = rowbase >> 9, nbase = rowbase & 511;

  bf16x8 a[2][6];
#pragma unroll
  for (int mm = 0; mm < 2; ++mm)
#pragma unroll
    for (int k = 0; k < 6; ++k) {
      const float* xp = x + (size_t)(rowbase + mm * 16 + li) * 192 + k * 32 + 8 * g;
      f32x4 x0 = *(const f32x4*)xp;
      f32x4 x1 = *(const f32x4*)(xp + 4);
      a[mm][k] = cvt2_bf16x8(x0, x1);
    }

  f32x4 acc[3][2][4];                  // [ncl][mm][n] — all static indices
#pragma unroll
  for (int ncl = 0; ncl < 3; ++ncl)
#pragma unroll
    for (int n = 0; n < 4; ++n) {
      int r = (wave * 3 + ncl) * 64 + n * 16 + li;
      float bb = 0.0f;
      if (r < 192) bb = qb[r];
      else if (r >= 384) bb = vb[r - 384];
      f32x4 v = {bb, bb, bb, bb};
      acc[ncl][0][n] = v; acc[ncl][1][n] = v;
    }
#pragma unroll
  for (int k = 0; k < 6; ++k)
#pragma unroll
    for (int ncl = 0; ncl < 3; ++ncl)
#pragma unroll
      for (int n = 0; n < 4; ++n) {
        int nc = wave * 3 + ncl;
        bf16x8 bf = *(const bf16x8*)(wbf + (size_t)(nc * 64 + n * 16 + li) * 192 + k * 32 + 8 * g);
        acc[ncl][0][n] = __builtin_amdgcn_mfma_f32_16x16x32_bf16(a[0][k], bf, acc[ncl][0][n], 0, 0, 0);
        acc[ncl][1][n] = __builtin_amdgcn_mfma_f32_16x16x32_bf16(a[1][k], bf, acc[ncl][1][n], 0, 0, 0);
      }

  // Deferred epilogues (serial; tile[wave] reused per ncl, same-wave only).
#pragma unroll
  for (int ncl = 0; ncl < 3; ++ncl) {
    int nc = wave * 3 + ncl;
    if (wave < 2) {
      float scale = (wave == 0) ? CQ : 1.0f;
#pragma unroll
      for (int n = 0; n < 4; ++n)
#pragma unroll
        for (int mm = 0; mm < 2; ++mm)
#pragma unroll
          for (int t = 0; t < 4; ++t)
            tile[wave][mm * 16 + 4 * g + t][n * 16 + li] = (__bf16)(acc[ncl][mm][n][t] * scale);
      int tok = lane & 31, hh = lane >> 5;
      int h = (nc * 2 + hh) % 6;
      __bf16* base = (wave == 0) ? Qo : Ko;
      __bf16* dst = base + ((size_t)(b * 6 + h) * 512 + nbase + tok) * 32;
#pragma unroll
      for (int kq = 0; kq < 4; ++kq)
        *(bf16x8*)(dst + kq * 8) = *(const bf16x8*)&tile[wave][tok][hh * 32 + kq * 8];
    } else {
#pragma unroll
      for (int n = 0; n < 4; ++n) {
        int rr = nc * 64 + n * 16 + li - 384, h = rr >> 5, d = rr & 31;
#pragma unroll
        for (int mm = 0; mm < 2; ++mm) {
          int nn = nbase + mm * 16 + 4 * g;
          bf16x4v pk;
#pragma unroll
          for (int t = 0; t < 4; ++t) pk[t] = (__bf16)acc[ncl][mm][n][t];
          *(bf16x4v*)(Vt + ((size_t)(b * 6 + h) * 32 + d) * 512 + nn) = pk;
        }
      }
    }
  }
}

// ---------------- k3: attention (VALU->MFMA offload for softmax) ------------
__global__ __launch_bounds__(256, 3) void attn_kernel(
    const u64* __restrict__ bits,      // (64,8,512) unmasked-bit words
    const _Float16* __restrict__ biasH,// (6,512,512) fp16, PERMUTED, *LOG2E
    const __bf16* __restrict__ Qw,     // (64*6,512,32), pre-scaled
    const __bf16* __restrict__ Kw,     // (64*6,512,32)
    const __bf16* __restrict__ Vt,     // (64*6,32,512)
    float* __restrict__ out)           // (64,6,512,32) fp32
{
  // 768 blocks. hw%8 = XCD; h slowest within XCD (bias slice L2-resident).
  int hw = blockIdx.x;
  int xcd = hw & 7, seq = hw >> 3;     // seq 0..95
  int h = seq >> 4;                    // 0..5  (slowest)
  int r = seq & 15;
  int b = xcd * 8 + (r >> 1);          // 8 windows per XCD
  int qt = r & 1;
  int lane = threadIdx.x & 63, wave = threadIdx.x >> 6;
  int g = lane >> 4, li = lane & 15;
  int qbase = qt * 256 + wave * 64;    // 64 q-rows per wave
  int bh = b * 6 + h;
  int gsh = 4 * g;

  const __bf16* Qb = Qw + (size_t)bh * 16384;
  const __bf16* Kb = Kw + (size_t)bh * 16384;
  const __bf16* Vb = Vt + (size_t)bh * 16384;
  const _Float16* biasb = biasH + (size_t)h * 262144 + g * 16;
  const u64* bitsb = bits + (size_t)b * 4096;

  bf16x8 qfrag[4];
#pragma unroll
  for (int qf = 0; qf < 4; ++qf)
    qfrag[qf] = *(const bf16x8*)(Qb + (qbase + qf * 16 + li) * 32 + 8 * g);

  // all-ones A-frag: l row-sum via the (idle) MFMA pipe
  union { unsigned short us[8]; bf16x8 v; } onesu;
#pragma unroll
  for (int i = 0; i < 8; ++i) onesu.us[i] = 0x3F80;   // bf16 1.0
  bf16x8 ones = onesu.v;

  f32x4 oacc[4][2] = {};        // [qf][df]: O^T frags (col=i, row=d)
  f32x4 lacc[4] = {};           // [qf]: row-sum l (every element equals l_i)

  for (int kb = 0; kb < 8; ++kb) {      // 64 keys per iteration
    int j64 = kb * 64;
    unsigned mbl[4], mbh[4];
#pragma unroll
    for (int qf = 0; qf < 4; ++qf) {
      u64 m64 = bitsb[(kb << 9) + qbase + qf * 16 + li] >> gsh;
      mbl[qf] = (unsigned)m64;
      mbh[qf] = (unsigned)(m64 >> 32);
    }
    bf16x8 kfr[4];
#pragma unroll
    for (int kf = 0; kf < 4; ++kf)
      kfr[kf] = *(const bf16x8*)(Kb + (j64 + kf * 16 + li) * 32 + 8 * g);
    bf16x8 vfr[2][2];
#pragma unroll
    for (int df = 0; df < 2; ++df)
#pragma unroll
      for (int c = 0; c < 2; ++c)
        vfr[df][c] = *(const bf16x8*)(Vb + (df * 16 + li) * 512 + j64 + c * 32 + 8 * g);
    // Repacked bias: lane's whole-iteration bias = 32B contiguous -> 2 loads.
    f16x8 hv8[4][2];
#pragma unroll
    for (int qf = 0; qf < 4; ++qf) {
      const _Float16* bp = biasb + (size_t)(qbase + qf * 16 + li) * 512 + j64;
      hv8[qf][0] = *(const f16x8*)(bp);       // kf0 (elems 0-3), kf1 (4-7)
      hv8[qf][1] = *(const f16x8*)(bp + 8);   // kf2, kf3
    }

    __builtin_amdgcn_s_setprio(1);
#pragma unroll
    for (int c = 0; c < 2; ++c) {
      unsigned lo[4][2], hi[4][2];      // [qf][kfl]
#pragma unroll
      for (int kfl = 0; kfl < 2; ++kfl) {
        int kf = c * 2 + kfl;
        const int hsel = kf >> 1, hoff = (kf & 1) * 4;
        const int bb0 = (kf & 1) * 16;  // bit base within the mask word
#pragma unroll
        for (int qf = 0; qf < 4; ++qf) {
          f16x8 hb = hv8[qf][hsel];
          f32x4 ci = {(float)hb[hoff], (float)hb[hoff + 1],
                      (float)hb[hoff + 2], (float)hb[hoff + 3]};
          f32x4 s = __builtin_amdgcn_mfma_f32_16x16x32_bf16(kfr[kf], qfrag[qf], ci, 0, 0, 0);
          unsigned mword = hsel ? mbh[qf] : mbl[qf];
          // sign-extract bit -> 0/~0, AND with exp2 bits (exp2>=0, exact).
          unsigned m0 = (unsigned)((int)(mword << (31 - (bb0 + 0))) >> 31);
          unsigned m1 = (unsigned)((int)(mword << (31 - (bb0 + 1))) >> 31);
          unsigned m2 = (unsigned)((int)(mword << (31 - (bb0 + 2))) >> 31);
          unsigned m3 = (unsigned)((int)(mword << (31 - (bb0 + 3))) >> 31);
          float p0 = __builtin_bit_cast(float,
              __builtin_bit_cast(unsigned, __builtin_amdgcn_exp2f(s[0])) & m0);
          float p1 = __builtin_bit_cast(float,
              __builtin_bit_cast(unsigned, __builtin_amdgcn_exp2f(s[1])) & m1);
          float p2 = __builtin_bit_cast(float,
              __builtin_bit_cast(unsigned, __builtin_amdgcn_exp2f(s[2])) & m2);
          float p3 = __builtin_bit_cast(float,
              __builtin_bit_cast(unsigned, __builtin_amdgcn_exp2f(s[3])) & m3);
          lo[qf][kfl] = pack2bf(p0, p1);
          hi[qf][kfl] = pack2bf(p2, p3);
        }
      }
      // In-register P^T relayout via permlane32_swap + permlane16_swap:
      //   {W(e0e1), W(e4e5)} = swap16(swap32(lo0, lo1))
      //   {W(e2e3), W(e6e7)} = swap16(swap32(hi0, hi1))
#pragma unroll
      for (int qf = 0; qf < 4; ++qf) {
        uint2v sl = __builtin_amdgcn_permlane32_swap(lo[qf][0], lo[qf][1], 0, 0);
        uint2v wl = __builtin_amdgcn_permlane16_swap(sl.x, sl.y, 0, 0);
        uint2v sh = __builtin_amdgcn_permlane32_swap(hi[qf][0], hi[qf][1], 0, 0);
        uint2v wh = __builtin_amdgcn_permlane16_swap(sh.x, sh.y, 0, 0);
        bf16x8 pf = frag_from_words(wl.x, wh.x, wl.y, wh.y);
        oacc[qf][0] = __builtin_amdgcn_mfma_f32_16x16x32_bf16(vfr[0][c], pf, oacc[qf][0], 0, 0, 0);
        oacc[qf][1] = __builtin_amdgcn_mfma_f32_16x16x32_bf16(vfr[1][c], pf, oacc[qf][1], 0, 0, 0);
        lacc[qf]    = __builtin_amdgcn_mfma_f32_16x16x32_bf16(ones, pf, lacc[qf], 0, 0, 0);
      }
    }
    __builtin_amdgcn_s_setprio(0);
  }

  // Epilogue: l already summed per q-row by the ones-MFMA (col = li).
#pragma unroll
  for (int qf = 0; qf < 4; ++qf) {
    float linv = 1.0f / lacc[qf][0];
#pragma unroll
    for (int df = 0; df < 2; ++df) {
      float* op = out + ((size_t)bh * 512 + qbase + qf * 16 + li) * 32 + df * 16 + 4 * g;
      f32x4 r2 = oacc[qf][df] * linv;
      *(f32x4*)op = r2;
    }
  }
}

extern "C" void kernel_launch(void* const* d_in, const int* in_sizes, int n_in,
                              void* d_out, int out_size, void* d_ws, size_t ws_size,
                              hipStream_t stream) {
  const float* x    = (const float*)d_in[0];
  const float* mask = (const float*)d_in[1];
  const float* wqkv = (const float*)d_in[2];
  const float* qb   = (const float*)d_in[3];
  const float* vb   = (const float*)d_in[4];
  const float* w1   = (const float*)d_in[5];
  const float* b1   = (const float*)d_in[6];
  const float* w2   = (const float*)d_in[7];
  const float* tbl  = (const float*)d_in[8];
  const int*   ridx = (const int*)d_in[9];
  float* out = (float*)d_out;

  char* ws = (char*)d_ws;
  float*    tab6  = (float*)(ws);                         //   131,072 B (3375x8 f32)
  _Float16* biasH = (_Float16*)(ws + 131072);             // 3,145,728 B
  u64*      bits  = (u64*)(ws + 131072 + 3145728);        // 2,097,152 B
  __bf16*   wbf   = (__bf16*)(ws + 131072 + 3145728 + 2097152);  // pad 262,144
  __bf16*   Q     = (__bf16*)(ws + 131072 + 3145728 + 2097152 + 262144);
  __bf16*   K     = Q + (size_t)64 * 6 * 512 * 32;        // 12,582,912 B each
  __bf16*   Vt    = K + (size_t)64 * 6 * 512 * 32;
  // total ws use: ~43.4 MB

  prep_kernel<<<PREP_GRID, 256, 0, stream>>>(wqkv, wbf, tbl, w1, b1, w2, tab6,
                                             mask, bits);
  mid_kernel<<<MID_GRID, 192, 0, stream>>>(x, wbf, qb, vb, Q, K, Vt,
                                           ridx, tab6, biasH);
  attn_kernel<<<768, 256, 0, stream>>>(bits, biasH, Q, K, Vt, out);
}

// Round 22
// 111.248 us; speedup vs baseline: 1.0587x; 1.0587x over previous
//
#include <hip/hip_runtime.h>
#include <hip/hip_bf16.h>

// WindowAttention3D: B=64 windows, N=512 tokens, H=6 heads, D=32, C=192.
// FINAL (best measured: 111.3us, reproduced twice). 3 launches:
//   k1 prep_kernel: maskbits || wconv || cpb MLP (tab6, padded 8/row)
//   k2 mid_kernel:  qkv bf16-MFMA GEMM (1024 blocks x 3 waves, wave=region,
//                   3 serial 64-col chunks) || bias_expand (x4 gather)
//   k3 attn_kernel: 4 waves x 64 q-rows, 8 kb-iters, no LDS; softmax row-sum
//                   on the MFMA pipe (ones-MFMA), bit-mask via sign-extract+
//                   AND on exp2 bits, s_setprio(1); swapped QK^T, PERMUTED
//                   f16x8 bias, permlane32/16_swap P relayout, exp2 softmax.

typedef __bf16 bf16x8 __attribute__((ext_vector_type(8)));
typedef __bf16 bf16x4v __attribute__((ext_vector_type(4)));
typedef float  f32x4  __attribute__((ext_vector_type(4)));
typedef _Float16 f16x4 __attribute__((ext_vector_type(4)));
typedef _Float16 f16x8 __attribute__((ext_vector_type(8)));
typedef unsigned uint2v __attribute__((ext_vector_type(2)));
typedef int int4v __attribute__((ext_vector_type(4)));
typedef unsigned long long u64;

#define LOG2E 1.4426950408889634f

__device__ __forceinline__ bf16x8 cvt2_bf16x8(f32x4 a, f32x4 b) {
  bf16x8 r;
  r[0] = (__bf16)a[0]; r[1] = (__bf16)a[1]; r[2] = (__bf16)a[2]; r[3] = (__bf16)a[3];
  r[4] = (__bf16)b[0]; r[5] = (__bf16)b[1]; r[6] = (__bf16)b[2]; r[7] = (__bf16)b[3];
  return r;
}

__device__ __forceinline__ unsigned pack2bf(float a, float b) {
  unsigned short ua = __builtin_bit_cast(unsigned short, (__bf16)a);
  unsigned short ub = __builtin_bit_cast(unsigned short, (__bf16)b);
  return (unsigned)ua | ((unsigned)ub << 16);
}

__device__ __forceinline__ bf16x8 frag_from_words(unsigned w0, unsigned w1,
                                                  unsigned w2, unsigned w3) {
  union { unsigned u[4]; bf16x8 v; } f;
  f.u[0] = w0; f.u[1] = w1; f.u[2] = w2; f.u[3] = w3;
  return f.v;
}

// ---------------- k1: prep (maskbits || wconv || cpb) -----------------------
#define PREP_MB    2048
#define PREP_WCONV 108
#define PREP_CPB   3375
#define PREP_GRID  (PREP_MB + PREP_WCONV + PREP_CPB)   // 5531

__global__ __launch_bounds__(256) void prep_kernel(
    const float* __restrict__ w, __bf16* __restrict__ wbf,
    const float* __restrict__ table, const float* __restrict__ w1,
    const float* __restrict__ b1, const float* __restrict__ w2,
    float* __restrict__ tab6,          // (3375,8) padded rows
    const float* __restrict__ m, u64* __restrict__ bits)
{
  __shared__ float red[4][6];
  int blk = blockIdx.x;
  if (blk < PREP_MB) {
    // maskbits: 8 consecutive elems/thread -> byte; 8 lanes -> one u64 word.
    int li8 = threadIdx.x & 7;
    for (size_t t = (size_t)blk * 256 + threadIdx.x;
         t < 2097152ull; t += (size_t)PREP_MB * 256) {
      const float* mp = m + t * 8;
      f32x4 v0 = *(const f32x4*)mp;
      f32x4 v1 = *(const f32x4*)(mp + 4);
      unsigned byte =
          (v0[0] == 0.f ? 1u : 0u)  | (v0[1] == 0.f ? 2u : 0u) |
          (v0[2] == 0.f ? 4u : 0u)  | (v0[3] == 0.f ? 8u : 0u) |
          (v1[0] == 0.f ? 16u : 0u) | (v1[1] == 0.f ? 32u : 0u) |
          (v1[2] == 0.f ? 64u : 0u) | (v1[3] == 0.f ? 128u : 0u);
      u64 part = (u64)byte << (8 * li8);
      part |= __shfl_xor(part, 1);
      part |= __shfl_xor(part, 2);
      part |= __shfl_xor(part, 4);
      if (li8 == 0) {
        int w_ = (int)(t >> 3);          // word index
        int b = w_ >> 12, i = (w_ >> 3) & 511, jw = w_ & 7;
        bits[(((size_t)b * 8 + jw) << 9) + i] = part;
      }
    }
  } else if (blk < PREP_MB + PREP_WCONV) {
    int t = (blk - PREP_MB) * 256 + threadIdx.x;
    f32x4 v = *(const f32x4*)(w + (size_t)t * 4);
    bf16x4v o;
    o[0] = (__bf16)v[0]; o[1] = (__bf16)v[1]; o[2] = (__bf16)v[2]; o[3] = (__bf16)v[3];
    *(bf16x4v*)(wbf + (size_t)t * 4) = o;
  } else {
    int p = blk - PREP_MB - PREP_WCONV;
    float c0 = table[p * 3 + 0], c1 = table[p * 3 + 1], c2 = table[p * 3 + 2];
    float acc[6] = {0.f, 0.f, 0.f, 0.f, 0.f, 0.f};
#pragma unroll
    for (int jj = 0; jj < 2; ++jj) {
      int j = threadIdx.x + jj * 256;
      float hv = w1[j * 3 + 0] * c0 + w1[j * 3 + 1] * c1 + w1[j * 3 + 2] * c2 + b1[j];
      hv = fmaxf(hv, 0.0f);
#pragma unroll
      for (int t = 0; t < 6; ++t) acc[t] += w2[t * 512 + j] * hv;
    }
#pragma unroll
    for (int t = 0; t < 6; ++t) {
      acc[t] += __shfl_xor(acc[t], 1);
      acc[t] += __shfl_xor(acc[t], 2);
      acc[t] += __shfl_xor(acc[t], 4);
      acc[t] += __shfl_xor(acc[t], 8);
      acc[t] += __shfl_xor(acc[t], 16);
      acc[t] += __shfl_xor(acc[t], 32);
    }
    int wave = threadIdx.x >> 6;
    if ((threadIdx.x & 63) == 0)
#pragma unroll
      for (int t = 0; t < 6; ++t) red[wave][t] = acc[t];
    __syncthreads();
    if (threadIdx.x < 6) {
      int t = threadIdx.x;
      float s = red[0][t] + red[1][t] + red[2][t] + red[3][t];
      float sig = 16.0f / (1.0f + expf(-s));
      tab6[p * 8 + t] = sig * LOG2E;    // pre-scale by log2e; row pitch 8
    }
  }
}

// ---------------- k2: mid (qkv || bias_expand) ------------------------------
#define MID_QKV  1024
#define MID_BIAS 342
#define MID_GRID (MID_QKV + MID_BIAS)   // 1366

__global__ __launch_bounds__(192) void mid_kernel(
    const float* __restrict__ x,       // (32768,192) fp32
    const __bf16* __restrict__ wbf,    // (576,192) bf16
    const float* __restrict__ qb,      // (192)
    const float* __restrict__ vb,      // (192)
    __bf16* __restrict__ Qo,           // (64*6,512,32)
    __bf16* __restrict__ Ko,           // (64*6,512,32)
    __bf16* __restrict__ Vt,           // (64*6,32,512)
    const int* __restrict__ relidx,    // (512,512)
    const float* __restrict__ tab6,    // (3375,8) padded
    _Float16* __restrict__ biasH)      // (6,512,512) fp16, PERMUTED, *LOG2E
{
  __shared__ __bf16 tile[2][32][72];   // per-wave private transpose staging
  if (blockIdx.x >= MID_QKV) {
    // ---- bias_expand x4: 4 consecutive output p (same i) per thread.
    // p = jblk*64 + g*16 + kf*4 + t  <-  j = jblk*64 + kf*16 + g*4 + t
    for (int q4 = (blockIdx.x - MID_QKV) * 192 + threadIdx.x; q4 < 65536;
         q4 += MID_BIAS * 192) {
      int ij = q4 * 4;
      int i = ij >> 9, p = ij & 511;
      int jblk = p >> 6, g = (p >> 4) & 3, kf = (p >> 2) & 3;
      int j = (jblk << 6) + kf * 16 + g * 4;
      int4v idx4 = *(const int4v*)(relidx + (i << 9) + j);
      float val[6][4];
#pragma unroll
      for (int u = 0; u < 4; ++u) {
        f32x4 lo = *(const f32x4*)(tab6 + (size_t)idx4[u] * 8);
        f32x4 hi = *(const f32x4*)(tab6 + (size_t)idx4[u] * 8 + 4);
        val[0][u] = lo[0]; val[1][u] = lo[1]; val[2][u] = lo[2];
        val[3][u] = lo[3]; val[4][u] = hi[0]; val[5][u] = hi[1];
      }
#pragma unroll
      for (int t6 = 0; t6 < 6; ++t6) {
        f16x4 o = {(_Float16)val[t6][0], (_Float16)val[t6][1],
                   (_Float16)val[t6][2], (_Float16)val[t6][3]};
        *(f16x4*)(biasH + (size_t)t6 * 262144 + ij) = o;
      }
    }
    return;
  }
  // ---- qkv
  const float CQ = 0.17677669529663687f * LOG2E;  // 1/sqrt(32) * log2e
  int lane = threadIdx.x & 63, wave = threadIdx.x >> 6;
  int g = lane >> 4, li = lane & 15;
  int rowbase = blockIdx.x * 32;
  int b = rowbase >> 9, nbase = rowbase & 511;

  bf16x8 a[2][6];
#pragma unroll
  for (int mm = 0; mm < 2; ++mm)
#pragma unroll
    for (int k = 0; k < 6; ++k) {
      const float* xp = x + (size_t)(rowbase + mm * 16 + li) * 192 + k * 32 + 8 * g;
      f32x4 x0 = *(const f32x4*)xp;
      f32x4 x1 = *(const f32x4*)(xp + 4);
      a[mm][k] = cvt2_bf16x8(x0, x1);
    }

  for (int ncl = 0; ncl < 3; ++ncl) {
    int nc = wave * 3 + ncl;           // output col chunk of 64 (region=wave)
    f32x4 acc[2][4];
#pragma unroll
    for (int n = 0; n < 4; ++n) {
      int r = nc * 64 + n * 16 + li;
      float bb = 0.0f;
      if (r < 192) bb = qb[r];
      else if (r >= 384) bb = vb[r - 384];
      f32x4 v = {bb, bb, bb, bb};
      acc[0][n] = v; acc[1][n] = v;
    }
#pragma unroll
    for (int k = 0; k < 6; ++k) {
#pragma unroll
      for (int n = 0; n < 4; ++n) {
        bf16x8 bf = *(const bf16x8*)(wbf + (size_t)(nc * 64 + n * 16 + li) * 192 + k * 32 + 8 * g);
        acc[0][n] = __builtin_amdgcn_mfma_f32_16x16x32_bf16(a[0][k], bf, acc[0][n], 0, 0, 0);
        acc[1][n] = __builtin_amdgcn_mfma_f32_16x16x32_bf16(a[1][k], bf, acc[1][n], 0, 0, 0);
      }
    }
    // Epilogue. tile[wave] written+read by the SAME wave only — no barrier.
    if (wave < 2) {
      float scale = (wave == 0) ? CQ : 1.0f;
#pragma unroll
      for (int n = 0; n < 4; ++n)
#pragma unroll
        for (int mm = 0; mm < 2; ++mm)
#pragma unroll
          for (int t = 0; t < 4; ++t)
            tile[wave][mm * 16 + 4 * g + t][n * 16 + li] = (__bf16)(acc[mm][n][t] * scale);
      int tok = lane & 31, hh = lane >> 5;
      int h = (nc * 2 + hh) % 6;
      __bf16* base = (wave == 0) ? Qo : Ko;
      __bf16* dst = base + ((size_t)(b * 6 + h) * 512 + nbase + tok) * 32;
#pragma unroll
      for (int kq = 0; kq < 4; ++kq)
        *(bf16x8*)(dst + kq * 8) = *(const bf16x8*)&tile[wave][tok][hh * 32 + kq * 8];
    } else {
#pragma unroll
      for (int n = 0; n < 4; ++n) {
        int rr = nc * 64 + n * 16 + li - 384, h = rr >> 5, d = rr & 31;
#pragma unroll
        for (int mm = 0; mm < 2; ++mm) {
          int nn = nbase + mm * 16 + 4 * g;
          bf16x4v pk;
#pragma unroll
          for (int t = 0; t < 4; ++t) pk[t] = (__bf16)acc[mm][n][t];
          *(bf16x4v*)(Vt + ((size_t)(b * 6 + h) * 32 + d) * 512 + nn) = pk;
        }
      }
    }
  }
}

// ---------------- k3: attention (VALU->MFMA offload for softmax) ------------
__global__ __launch_bounds__(256, 3) void attn_kernel(
    const u64* __restrict__ bits,      // (64,8,512) unmasked-bit words
    const _Float16* __restrict__ biasH,// (6,512,512) fp16, PERMUTED, *LOG2E
    const __bf16* __restrict__ Qw,     // (64*6,512,32), pre-scaled
    const __bf16* __restrict__ Kw,     // (64*6,512,32)
    const __bf16* __restrict__ Vt,     // (64*6,32,512)
    float* __restrict__ out)           // (64,6,512,32) fp32
{
  // 768 blocks. hw%8 = XCD; h slowest within XCD (bias slice L2-resident).
  int hw = blockIdx.x;
  int xcd = hw & 7, seq = hw >> 3;     // seq 0..95
  int h = seq >> 4;                    // 0..5  (slowest)
  int r = seq & 15;
  int b = xcd * 8 + (r >> 1);          // 8 windows per XCD
  int qt = r & 1;
  int lane = threadIdx.x & 63, wave = threadIdx.x >> 6;
  int g = lane >> 4, li = lane & 15;
  int qbase = qt * 256 + wave * 64;    // 64 q-rows per wave
  int bh = b * 6 + h;
  int gsh = 4 * g;

  const __bf16* Qb = Qw + (size_t)bh * 16384;
  const __bf16* Kb = Kw + (size_t)bh * 16384;
  const __bf16* Vb = Vt + (size_t)bh * 16384;
  const _Float16* biasb = biasH + (size_t)h * 262144 + g * 16;
  const u64* bitsb = bits + (size_t)b * 4096;

  bf16x8 qfrag[4];
#pragma unroll
  for (int qf = 0; qf < 4; ++qf)
    qfrag[qf] = *(const bf16x8*)(Qb + (qbase + qf * 16 + li) * 32 + 8 * g);

  // all-ones A-frag: l row-sum via the (idle) MFMA pipe
  union { unsigned short us[8]; bf16x8 v; } onesu;
#pragma unroll
  for (int i = 0; i < 8; ++i) onesu.us[i] = 0x3F80;   // bf16 1.0
  bf16x8 ones = onesu.v;

  f32x4 oacc[4][2] = {};        // [qf][df]: O^T frags (col=i, row=d)
  f32x4 lacc[4] = {};           // [qf]: row-sum l (every element equals l_i)

  for (int kb = 0; kb < 8; ++kb) {      // 64 keys per iteration
    int j64 = kb * 64;
    unsigned mbl[4], mbh[4];
#pragma unroll
    for (int qf = 0; qf < 4; ++qf) {
      u64 m64 = bitsb[(kb << 9) + qbase + qf * 16 + li] >> gsh;
      mbl[qf] = (unsigned)m64;
      mbh[qf] = (unsigned)(m64 >> 32);
    }
    bf16x8 kfr[4];
#pragma unroll
    for (int kf = 0; kf < 4; ++kf)
      kfr[kf] = *(const bf16x8*)(Kb + (j64 + kf * 16 + li) * 32 + 8 * g);
    bf16x8 vfr[2][2];
#pragma unroll
    for (int df = 0; df < 2; ++df)
#pragma unroll
      for (int c = 0; c < 2; ++c)
        vfr[df][c] = *(const bf16x8*)(Vb + (df * 16 + li) * 512 + j64 + c * 32 + 8 * g);
    // Repacked bias: lane's whole-iteration bias = 32B contiguous -> 2 loads.
    f16x8 hv8[4][2];
#pragma unroll
    for (int qf = 0; qf < 4; ++qf) {
      const _Float16* bp = biasb + (size_t)(qbase + qf * 16 + li) * 512 + j64;
      hv8[qf][0] = *(const f16x8*)(bp);       // kf0 (elems 0-3), kf1 (4-7)
      hv8[qf][1] = *(const f16x8*)(bp + 8);   // kf2, kf3
    }

    __builtin_amdgcn_s_setprio(1);
#pragma unroll
    for (int c = 0; c < 2; ++c) {
      unsigned lo[4][2], hi[4][2];      // [qf][kfl]
#pragma unroll
      for (int kfl = 0; kfl < 2; ++kfl) {
        int kf = c * 2 + kfl;
        const int hsel = kf >> 1, hoff = (kf & 1) * 4;
        const int bb0 = (kf & 1) * 16;  // bit base within the mask word
#pragma unroll
        for (int qf = 0; qf < 4; ++qf) {
          f16x8 hb = hv8[qf][hsel];
          f32x4 ci = {(float)hb[hoff], (float)hb[hoff + 1],
                      (float)hb[hoff + 2], (float)hb[hoff + 3]};
          f32x4 s = __builtin_amdgcn_mfma_f32_16x16x32_bf16(kfr[kf], qfrag[qf], ci, 0, 0, 0);
          unsigned mword = hsel ? mbh[qf] : mbl[qf];
          // sign-extract bit -> 0/~0, AND with exp2 bits (exp2>=0, exact).
          unsigned m0 = (unsigned)((int)(mword << (31 - (bb0 + 0))) >> 31);
          unsigned m1 = (unsigned)((int)(mword << (31 - (bb0 + 1))) >> 31);
          unsigned m2 = (unsigned)((int)(mword << (31 - (bb0 + 2))) >> 31);
          unsigned m3 = (unsigned)((int)(mword << (31 - (bb0 + 3))) >> 31);
          float p0 = __builtin_bit_cast(float,
              __builtin_bit_cast(unsigned, __builtin_amdgcn_exp2f(s[0])) & m0);
          float p1 = __builtin_bit_cast(float,
              __builtin_bit_cast(unsigned, __builtin_amdgcn_exp2f(s[1])) & m1);
          float p2 = __builtin_bit_cast(float,
              __builtin_bit_cast(unsigned, __builtin_amdgcn_exp2f(s[2])) & m2);
          float p3 = __builtin_bit_cast(float,
              __builtin_bit_cast(unsigned, __builtin_amdgcn_exp2f(s[3])) & m3);
          lo[qf][kfl] = pack2bf(p0, p1);
          hi[qf][kfl] = pack2bf(p2, p3);
        }
      }
      // In-register P^T relayout via permlane32_swap + permlane16_swap:
      //   {W(e0e1), W(e4e5)} = swap16(swap32(lo0, lo1))
      //   {W(e2e3), W(e6e7)} = swap16(swap32(hi0, hi1))
#pragma unroll
      for (int qf = 0; qf < 4; ++qf) {
        uint2v sl = __builtin_amdgcn_permlane32_swap(lo[qf][0], lo[qf][1], 0, 0);
        uint2v wl = __builtin_amdgcn_permlane16_swap(sl.x, sl.y, 0, 0);
        uint2v sh = __builtin_amdgcn_permlane32_swap(hi[qf][0], hi[qf][1], 0, 0);
        uint2v wh = __builtin_amdgcn_permlane16_swap(sh.x, sh.y, 0, 0);
        bf16x8 pf = frag_from_words(wl.x, wh.x, wl.y, wh.y);
        oacc[qf][0] = __builtin_amdgcn_mfma_f32_16x16x32_bf16(vfr[0][c], pf, oacc[qf][0], 0, 0, 0);
        oacc[qf][1] = __builtin_amdgcn_mfma_f32_16x16x32_bf16(vfr[1][c], pf, oacc[qf][1], 0, 0, 0);
        lacc[qf]    = __builtin_amdgcn_mfma_f32_16x16x32_bf16(ones, pf, lacc[qf], 0, 0, 0);
      }
    }
    __builtin_amdgcn_s_setprio(0);
  }

  // Epilogue: l already summed per q-row by the ones-MFMA (col = li).
#pragma unroll
  for (int qf = 0; qf < 4; ++qf) {
    float linv = 1.0f / lacc[qf][0];
#pragma unroll
    for (int df = 0; df < 2; ++df) {
      float* op = out + ((size_t)bh * 512 + qbase + qf * 16 + li) * 32 + df * 16 + 4 * g;
      f32x4 r2 = oacc[qf][df] * linv;
      *(f32x4*)op = r2;
    }
  }
}

extern "C" void kernel_launch(void* const* d_in, const int* in_sizes, int n_in,
                              void* d_out, int out_size, void* d_ws, size_t ws_size,
                              hipStream_t stream) {
  const float* x    = (const float*)d_in[0];
  const float* mask = (const float*)d_in[1];
  const float* wqkv = (const float*)d_in[2];
  const float* qb   = (const float*)d_in[3];
  const float* vb   = (const float*)d_in[4];
  const float* w1   = (const float*)d_in[5];
  const float* b1   = (const float*)d_in[6];
  const float* w2   = (const float*)d_in[7];
  const float* tbl  = (const float*)d_in[8];
  const int*   ridx = (const int*)d_in[9];
  float* out = (float*)d_out;

  char* ws = (char*)d_ws;
  float*    tab6  = (float*)(ws);                         //   131,072 B (3375x8 f32)
  _Float16* biasH = (_Float16*)(ws + 131072);             // 3,145,728 B
  u64*      bits  = (u64*)(ws + 131072 + 3145728);        // 2,097,152 B
  __bf16*   wbf   = (__bf16*)(ws + 131072 + 3145728 + 2097152);  // pad 262,144
  __bf16*   Q     = (__bf16*)(ws + 131072 + 3145728 + 2097152 + 262144);
  __bf16*   K     = Q + (size_t)64 * 6 * 512 * 32;        // 12,582,912 B each
  __bf16*   Vt    = K + (size_t)64 * 6 * 512 * 32;
  // total ws use: ~43.4 MB

  prep_kernel<<<PREP_GRID, 256, 0, stream>>>(wqkv, wbf, tbl, w1, b1, w2, tab6,
                                             mask, bits);
  mid_kernel<<<MID_GRID, 192, 0, stream>>>(x, wbf, qb, vb, Q, K, Vt,
                                           ridx, tab6, biasH);
  attn_kernel<<<768, 256, 0, stream>>>(bits, biasH, Q, K, Vt, out);
}